// Round 1
// baseline (1583.707 us; speedup 1.0000x reference)
//
#include <hip/hip_runtime.h>
#include <hip/hip_bf16.h>

// LSH attention (Reformer-style), B=16, S=4096, D=128, H=8, bucket=64.
// Pipeline: normalize -> hash (double-precision argmax) -> counting sort ->
// chunked attention (unnormalized exp sums, atomic accumulate) -> divide.

#define B_ 16
#define S_ 4096
#define D_ 128
#define H_ 8
#define NB_ 64          // n_buckets
#define C_ 512          // H * NB = chunks per batch
#define W_ 64           // bucket/window size

// ---------------------------------------------------------------- normalize
__global__ __launch_bounds__(256) void norm_kernel(const float* __restrict__ qk,
                                                   float* __restrict__ knorm) {
    int wave = threadIdx.x >> 6;
    int lane = threadIdx.x & 63;
    size_t row = (size_t)blockIdx.x * 4 + wave;
    const float2* src = (const float2*)(qk + row * D_);
    float2 vv = src[lane];
    float ss = vv.x * vv.x + vv.y * vv.y;
    #pragma unroll
    for (int m = 1; m < 64; m <<= 1) ss += __shfl_xor(ss, m, 64);
    float nrm = sqrtf(ss);
    float sc = 1.0f / fmaxf(nrm, 1e-12f);
    ((float2*)(knorm + row * D_))[lane] = make_float2(vv.x * sc, vv.y * sc);
}

// ---------------------------------------------------------------- hashing
// buckets[b,h,t] = argmax over [r_0..r_31, -r_0..-r_31] of r_i = qk[b,t,:].rot[:,h,i]
// Dots computed in double: f32*f32 products are exact in f64, so the argmax is
// (effectively) the true one -> minimal flip risk vs. reference.
__global__ __launch_bounds__(256) void hash_kernel(const float* __restrict__ qk,
                                                   const float* __restrict__ rot,
                                                   int* __restrict__ buckets) {
    __shared__ float qtile[64 * 132];   // 64 tokens x 128 dims, padded row 132
    __shared__ float rtile[128 * 32];   // rot[:, h, :]
    int b = blockIdx.x >> 6;
    int tile = blockIdx.x & 63;
    int tid = threadIdx.x;

    const float* qbase = qk + ((size_t)b * S_ + (size_t)tile * 64) * D_;
    #pragma unroll
    for (int u = 0; u < 8; ++u) {
        int fi = u * 256 + tid;          // float4 index 0..2047
        int row = fi >> 5, c = fi & 31;
        float4 vv = ((const float4*)qbase)[fi];
        *((float4*)(qtile + row * 132 + c * 4)) = vv;
    }

    int tok = tid >> 2, part = tid & 3;
    int t = tile * 64 + tok;

    for (int h = 0; h < H_; ++h) {
        __syncthreads();
        #pragma unroll
        for (int u = 0; u < 4; ++u) {
            int fi = u * 256 + tid;      // 0..1023 float4s of rtile
            int f = fi >> 3, i4 = fi & 7;
            ((float4*)rtile)[f * 8 + i4] = ((const float4*)rot)[f * 64 + h * 8 + i4];
        }
        __syncthreads();

        double pd[8] = {0, 0, 0, 0, 0, 0, 0, 0};
        #pragma unroll 2
        for (int f = 0; f < 128; ++f) {
            double q = (double)qtile[tok * 132 + f];
            float4 r0 = *((const float4*)(rtile + f * 32 + part * 8));
            float4 r1 = *((const float4*)(rtile + f * 32 + part * 8 + 4));
            pd[0] = fma(q, (double)r0.x, pd[0]);
            pd[1] = fma(q, (double)r0.y, pd[1]);
            pd[2] = fma(q, (double)r0.z, pd[2]);
            pd[3] = fma(q, (double)r0.w, pd[3]);
            pd[4] = fma(q, (double)r1.x, pd[4]);
            pd[5] = fma(q, (double)r1.y, pd[5]);
            pd[6] = fma(q, (double)r1.z, pd[6]);
            pd[7] = fma(q, (double)r1.w, pd[7]);
        }

        // local argmax with first-index tie-break over candidates (r_i, i), (-r_i, i+32)
        double bv = -1e300; int bi = 0;
        #pragma unroll
        for (int ii = 0; ii < 8; ++ii) {
            int i = part * 8 + ii;
            double v = pd[ii];
            if (v > bv || (v == bv && i < bi)) { bv = v; bi = i; }
            double nv = -v; int ni = i + 32;
            if (nv > bv || (nv == bv && ni < bi)) { bv = nv; bi = ni; }
        }
        #pragma unroll
        for (int m = 1; m <= 2; m <<= 1) {
            double ov = __shfl_xor(bv, m, 64);
            int oi = __shfl_xor(bi, m, 64);
            if (ov > bv || (ov == bv && oi < bi)) { bv = ov; bi = oi; }
        }
        if (part == 0) buckets[(((size_t)b * H_ + h) << 12) + t] = bi;
    }
}

// ---------------------------------------------------------------- stable counting sort
// One block per (b,h): sort 4096 tokens by bucket (stable in t).
// st[(b*H+h)*S + pos] = original token index.
__global__ __launch_bounds__(256) void sort_kernel(const int* __restrict__ buckets,
                                                   int* __restrict__ st) {
    __shared__ unsigned short hist[256][64];  // [chunk][bucket]
    __shared__ int base[64];
    __shared__ int totals[64];
    int tid = threadIdx.x;
    const int* bkrow = buckets + (size_t)blockIdx.x * S_;

    unsigned int* h32 = (unsigned int*)hist;
    #pragma unroll
    for (int u = 0; u < 32; ++u) h32[u * 256 + tid] = 0;
    __syncthreads();

    #pragma unroll
    for (int u = 0; u < 16; ++u) {
        int t = tid * 16 + u;
        int bk = bkrow[t];
        hist[tid][bk]++;
    }
    __syncthreads();

    if (tid < 64) {
        int bucket = tid;
        int run = 0;
        for (int ch = 0; ch < 256; ++ch) {
            int v = hist[ch][bucket];
            hist[ch][bucket] = (unsigned short)run;
            run += v;
        }
        totals[bucket] = run;
    }
    __syncthreads();
    if (tid == 0) {
        int acc = 0;
        for (int k = 0; k < 64; ++k) { base[k] = acc; acc += totals[k]; }
    }
    __syncthreads();

    int* strow = st + (size_t)blockIdx.x * S_;
    #pragma unroll
    for (int u = 0; u < 16; ++u) {
        int t = tid * 16 + u;
        int bk = bkrow[t];
        int off = hist[tid][bk];
        hist[tid][bk] = (unsigned short)(off + 1);
        strow[base[bk] + off] = t;
    }
}

// ---------------------------------------------------------------- attention
// One block per (b, chunk c). 64 queries x 128 keys (chunks c and c-1 mod 512).
// out_num[b,t,:] += sum_j exp(dots_j) * v_j ; den[b,t] += sum_j exp(dots_j).
// (equivalent to reference's per-round softmax + cross-round LSE combine)
__global__ __launch_bounds__(256) void attn_kernel(const float* __restrict__ qk,
                                                   const float* __restrict__ knorm,
                                                   const float* __restrict__ vglob,
                                                   const int* __restrict__ st,
                                                   float* __restrict__ outnum,
                                                   float* __restrict__ den) {
    __shared__ int tq[64];
    __shared__ int tk[64];
    __shared__ float kv[64 * 128];   // 32 KB, reused for K-hat then V

    int bc = blockIdx.x;
    int b = bc >> 9;
    int c = bc & 511;
    int tid = threadIdx.x;
    int qid = tid >> 2;
    int part = tid & 3;
    const int* stb = st + ((size_t)b << 15);

    if (tid < 64) tq[tid] = stb[c * 64 + tid];
    __syncthreads();
    int myt = tq[qid];

    // q in registers: this thread owns dims d = (u*4+part)*4 .. +3  (u = 0..7)
    const float* qrow = qk + (((size_t)b << 12) + myt) * D_;
    float4 q4[8];
    #pragma unroll
    for (int u = 0; u < 8; ++u) q4[u] = ((const float4*)qrow)[u * 4 + part];

    float4 o4[8] = {};
    float densum = 0.0f;
    const float scale = (float)0.08838834764831845;  // D^-0.5

    for (int kci = 0; kci < 2; ++kci) {
        int kc = (kci == 0) ? c : ((c + 511) & 511);
        __syncthreads();  // prior-iteration readers of kv/tk done
        if (tid < 64) tk[tid] = stb[kc * 64 + tid];
        __syncthreads();

        // stage K-hat
        #pragma unroll
        for (int u = 0; u < 8; ++u) {
            int fi = u * 256 + tid;
            int row = fi >> 5, cc = fi & 31;
            ((float4*)kv)[fi] =
                ((const float4*)(knorm + (((size_t)b << 12) + tk[row]) * D_))[cc];
        }
        __syncthreads();

        float e[64];
        #pragma unroll
        for (int g = 0; g < 4; ++g) {
            float pd[16] = {};
            #pragma unroll
            for (int u = 0; u < 8; ++u) {
                float4 q = q4[u];
                #pragma unroll
                for (int jj = 0; jj < 16; ++jj) {
                    float4 k = ((const float4*)kv)[(g * 16 + jj) * 32 + u * 4 + part];
                    pd[jj] += q.x * k.x + q.y * k.y + q.z * k.z + q.w * k.w;
                }
            }
            #pragma unroll
            for (int jj = 0; jj < 16; ++jj) {
                float s = pd[jj];
                s += __shfl_xor(s, 1, 64);
                s += __shfl_xor(s, 2, 64);
                int j = g * 16 + jj;
                e[j] = (tk[j] == myt) ? 0.0f : __expf(s * scale);
            }
        }
        __syncthreads();

        // stage V (overwrites kv)
        #pragma unroll
        for (int u = 0; u < 8; ++u) {
            int fi = u * 256 + tid;
            int row = fi >> 5, cc = fi & 31;
            ((float4*)kv)[fi] =
                ((const float4*)(vglob + (((size_t)b << 12) + tk[row]) * D_))[cc];
        }
        __syncthreads();

        #pragma unroll
        for (int j = 0; j < 64; ++j) {
            float ee = e[j];
            densum += ee;
            #pragma unroll
            for (int u = 0; u < 8; ++u) {
                float4 vv = ((const float4*)kv)[j * 32 + u * 4 + part];
                o4[u].x += ee * vv.x;
                o4[u].y += ee * vv.y;
                o4[u].z += ee * vv.z;
                o4[u].w += ee * vv.w;
            }
        }
    }

    float* obase = outnum + (((size_t)b << 12) + myt) * D_;
    #pragma unroll
    for (int u = 0; u < 8; ++u) {
        int d0 = (u * 4 + part) * 4;
        atomicAdd(obase + d0 + 0, o4[u].x);
        atomicAdd(obase + d0 + 1, o4[u].y);
        atomicAdd(obase + d0 + 2, o4[u].z);
        atomicAdd(obase + d0 + 3, o4[u].w);
    }
    if (part == 0) atomicAdd(den + (((size_t)b << 12) + myt), densum);
}

// ---------------------------------------------------------------- divide
__global__ __launch_bounds__(256) void div_kernel(float* __restrict__ out,
                                                  const float* __restrict__ den) {
    int i = blockIdx.x * 256 + threadIdx.x;  // float4 index, total B*S*D/4
    float4 o = ((float4*)out)[i];
    float dn = den[i >> 5];
    ((float4*)out)[i] = make_float4(o.x / dn, o.y / dn, o.z / dn, o.w / dn);
}

// ---------------------------------------------------------------- launch
extern "C" void kernel_launch(void* const* d_in, const int* in_sizes, int n_in,
                              void* d_out, int out_size, void* d_ws, size_t ws_size,
                              hipStream_t stream) {
    const float* qk  = (const float*)d_in[0];
    const float* v   = (const float*)d_in[1];
    const float* rot = (const float*)d_in[2];
    float* out = (float*)d_out;

    char* ws = (char*)d_ws;
    float* knorm  = (float*)ws;                       // 33,554,432 B
    int* buckets  = (int*)(ws + 33554432);            //  2,097,152 B
    int* st       = (int*)(ws + 35651584);            //  2,097,152 B
    float* den    = (float*)(ws + 37748736);          //    262,144 B

    hipMemsetAsync(out, 0, (size_t)B_ * S_ * D_ * 4, stream);
    hipMemsetAsync(den, 0, (size_t)B_ * S_ * 4, stream);

    norm_kernel<<<B_ * S_ / 4, 256, 0, stream>>>(qk, knorm);
    hash_kernel<<<B_ * (S_ / 64), 256, 0, stream>>>(qk, rot, buckets);
    sort_kernel<<<B_ * H_, 256, 0, stream>>>(buckets, st);
    attn_kernel<<<B_ * C_, 256, 0, stream>>>(qk, knorm, v, st, out, den);
    div_kernel<<<B_ * S_ * D_ / 4 / 256, 256, 0, stream>>>(out, den);
}

// Round 2
// 509.578 us; speedup vs baseline: 3.1079x; 3.1079x over previous
//
#include <hip/hip_runtime.h>
#include <hip/hip_bf16.h>

// LSH attention (Reformer-style), B=16, S=4096, D=128, H=8, bucket=64.
// Pipeline: normalize -> hash (double-precision argmax) -> counting sort ->
// MFMA chunked attention (bf16 3-term split, unnormalized exp sums, atomics)
// -> divide.

#define B_ 16
#define S_ 4096
#define D_ 128
#define H_ 8
#define NB_ 64          // n_buckets
#define C_ 512          // H * NB = chunks per batch
#define W_ 64           // bucket/window size

typedef __attribute__((ext_vector_type(8))) short bf16x8;
typedef __attribute__((ext_vector_type(4))) short short4v;
typedef __attribute__((ext_vector_type(4))) float f32x4;
typedef __attribute__((ext_vector_type(4))) int int4v;

__device__ __forceinline__ short f2bf(float x) {
    __hip_bfloat16 b = __float2bfloat16(x);   // RNE
    return *reinterpret_cast<short*>(&b);
}
__device__ __forceinline__ float bf2f(short h) {
    unsigned int u = ((unsigned int)(unsigned short)h) << 16;
    float f;
    __builtin_memcpy(&f, &u, 4);
    return f;
}

// ---------------------------------------------------------------- normalize
__global__ __launch_bounds__(256) void norm_kernel(const float* __restrict__ qk,
                                                   float* __restrict__ knorm) {
    int wave = threadIdx.x >> 6;
    int lane = threadIdx.x & 63;
    size_t row = (size_t)blockIdx.x * 4 + wave;
    const float2* src = (const float2*)(qk + row * D_);
    float2 vv = src[lane];
    float ss = vv.x * vv.x + vv.y * vv.y;
    #pragma unroll
    for (int m = 1; m < 64; m <<= 1) ss += __shfl_xor(ss, m, 64);
    float nrm = sqrtf(ss);
    float sc = 1.0f / fmaxf(nrm, 1e-12f);
    ((float2*)(knorm + row * D_))[lane] = make_float2(vv.x * sc, vv.y * sc);
}

// ---------------------------------------------------------------- hashing
__global__ __launch_bounds__(256) void hash_kernel(const float* __restrict__ qk,
                                                   const float* __restrict__ rot,
                                                   int* __restrict__ buckets) {
    __shared__ float qtile[64 * 132];
    __shared__ float rtile[128 * 32];
    int b = blockIdx.x >> 6;
    int tile = blockIdx.x & 63;
    int tid = threadIdx.x;

    const float* qbase = qk + ((size_t)b * S_ + (size_t)tile * 64) * D_;
    #pragma unroll
    for (int u = 0; u < 8; ++u) {
        int fi = u * 256 + tid;
        int row = fi >> 5, c = fi & 31;
        float4 vv = ((const float4*)qbase)[fi];
        *((float4*)(qtile + row * 132 + c * 4)) = vv;
    }

    int tok = tid >> 2, part = tid & 3;
    int t = tile * 64 + tok;

    for (int h = 0; h < H_; ++h) {
        __syncthreads();
        #pragma unroll
        for (int u = 0; u < 4; ++u) {
            int fi = u * 256 + tid;
            int f = fi >> 3, i4 = fi & 7;
            ((float4*)rtile)[f * 8 + i4] = ((const float4*)rot)[f * 64 + h * 8 + i4];
        }
        __syncthreads();

        double pd[8] = {0, 0, 0, 0, 0, 0, 0, 0};
        #pragma unroll 2
        for (int f = 0; f < 128; ++f) {
            double q = (double)qtile[tok * 132 + f];
            float4 r0 = *((const float4*)(rtile + f * 32 + part * 8));
            float4 r1 = *((const float4*)(rtile + f * 32 + part * 8 + 4));
            pd[0] = fma(q, (double)r0.x, pd[0]);
            pd[1] = fma(q, (double)r0.y, pd[1]);
            pd[2] = fma(q, (double)r0.z, pd[2]);
            pd[3] = fma(q, (double)r0.w, pd[3]);
            pd[4] = fma(q, (double)r1.x, pd[4]);
            pd[5] = fma(q, (double)r1.y, pd[5]);
            pd[6] = fma(q, (double)r1.z, pd[6]);
            pd[7] = fma(q, (double)r1.w, pd[7]);
        }

        double bv = -1e300; int bi = 0;
        #pragma unroll
        for (int ii = 0; ii < 8; ++ii) {
            int i = part * 8 + ii;
            double v = pd[ii];
            if (v > bv || (v == bv && i < bi)) { bv = v; bi = i; }
            double nv = -v; int ni = i + 32;
            if (nv > bv || (nv == bv && ni < bi)) { bv = nv; bi = ni; }
        }
        #pragma unroll
        for (int m = 1; m <= 2; m <<= 1) {
            double ov = __shfl_xor(bv, m, 64);
            int oi = __shfl_xor(bi, m, 64);
            if (ov > bv || (ov == bv && oi < bi)) { bv = ov; bi = oi; }
        }
        if (part == 0) buckets[(((size_t)b * H_ + h) << 12) + t] = bi;
    }
}

// ---------------------------------------------------------------- stable counting sort
__global__ __launch_bounds__(256) void sort_kernel(const int* __restrict__ buckets,
                                                   int* __restrict__ st) {
    __shared__ unsigned short hist[256][64];
    __shared__ int base[64];
    __shared__ int totals[64];
    int tid = threadIdx.x;
    const int* bkrow = buckets + (size_t)blockIdx.x * S_;

    unsigned int* h32 = (unsigned int*)hist;
    #pragma unroll
    for (int u = 0; u < 32; ++u) h32[u * 256 + tid] = 0;
    __syncthreads();

    #pragma unroll
    for (int u = 0; u < 16; ++u) {
        int t = tid * 16 + u;
        int bk = bkrow[t];
        hist[tid][bk]++;
    }
    __syncthreads();

    if (tid < 64) {
        int bucket = tid;
        int run = 0;
        for (int ch = 0; ch < 256; ++ch) {
            int v = hist[ch][bucket];
            hist[ch][bucket] = (unsigned short)run;
            run += v;
        }
        totals[bucket] = run;
    }
    __syncthreads();
    if (tid == 0) {
        int acc = 0;
        for (int k = 0; k < 64; ++k) { base[k] = acc; acc += totals[k]; }
    }
    __syncthreads();

    int* strow = st + (size_t)blockIdx.x * S_;
    #pragma unroll
    for (int u = 0; u < 16; ++u) {
        int t = tid * 16 + u;
        int bk = bkrow[t];
        int off = hist[tid][bk];
        hist[tid][bk] = (unsigned short)(off + 1);
        strow[base[bk] + off] = t;
    }
}

// ---------------------------------------------------------------- in-reg 4x4 transpose
// Threads g=0..3 (lanes l, l^16, l^32, l^48) each hold v = row g (cols 0..3).
// After: w_[i] = element (row i, col g).
__device__ __forceinline__ void transpose4(const float4 v, int g, float (&w_)[4]) {
    bool b0 = (g & 1) != 0, b1 = (g & 2) != 0;
    float k0 = b1 ? v.z : v.x;
    float k1 = b1 ? v.w : v.y;
    float s0 = b1 ? v.x : v.z;
    float s1 = b1 ? v.y : v.w;
    float r0 = __shfl_xor(s0, 32, 64);
    float r1 = __shfl_xor(s1, 32, 64);
    float kq_ = b0 ? k1 : k0;
    float rq_ = b0 ? r1 : r0;
    float sk  = b0 ? k0 : k1;
    float sr  = b0 ? r0 : r1;
    float tk_ = __shfl_xor(sk, 16, 64);
    float tr_ = __shfl_xor(sr, 16, 64);
    float A0 = b0 ? tk_ : kq_;
    float A1 = b0 ? kq_ : tk_;
    float B0 = b0 ? tr_ : rq_;
    float B1 = b0 ? rq_ : tr_;
    w_[0] = b1 ? B0 : A0;
    w_[1] = b1 ? B1 : A1;
    w_[2] = b1 ? A0 : B0;
    w_[3] = b1 ? A1 : B1;
}

// ---------------------------------------------------------------- MFMA attention
// One block per (b, chunk c): 64 queries vs 128 keys (chunks c, c-1 mod 512).
// dots^T = K_hat . Q^T via mfma_f32_16x16x32_bf16 (3-term bf16 split),
// P redistributed in-register via shuffles, PV = P . V via MFMA with V
// transposed in-register at staging into a subtiled [kg][d][8] LDS layout.
__global__ __launch_bounds__(256) void attn_mfma_kernel(
        const float* __restrict__ qk, const float* __restrict__ knorm,
        const float* __restrict__ vglob, const int* __restrict__ st,
        float* __restrict__ outnum, float* __restrict__ den) {
    __shared__ int tq_s[64];
    __shared__ int tk_s[64];
    // union buffer: khi [64][136] @0, klo @8704 | vhi [8][128][8] @0, vlo @8192
    __shared__ short kvs[17408];

    const int bc = blockIdx.x;
    const int b  = bc >> 9;
    const int c  = bc & 511;
    const int tid = threadIdx.x;
    const int w   = tid >> 6;   // wave 0..3
    const int l   = tid & 63;
    const int g   = l >> 4;     // quad 0..3
    const int m   = l & 15;

    const int* stb = st + ((size_t)b << 15);
    if (tid < 64) tq_s[tid] = stb[c * 64 + tid];
    __syncthreads();

    const int qtok_m = tq_s[w * 16 + m];   // this lane's q column token

    // ---- Q B-fragments (col=m, k-elems d = s4*32 + g*8 + j), scale folded
    bf16x8 qh[4], ql[4];
    {
        const float scale = 0.08838834764831845f;   // D^-0.5
        const float* qrow = qk + (((size_t)b << 12) + qtok_m) * D_;
        #pragma unroll
        for (int s4 = 0; s4 < 4; ++s4) {
            float4 xa = *(const float4*)(qrow + s4 * 32 + g * 8);
            float4 xb = *(const float4*)(qrow + s4 * 32 + g * 8 + 4);
            float xv[8] = {xa.x, xa.y, xa.z, xa.w, xb.x, xb.y, xb.z, xb.w};
            #pragma unroll
            for (int j = 0; j < 8; ++j) {
                float v = xv[j] * scale;
                short h = f2bf(v);
                qh[s4][j] = h;
                ql[s4][j] = f2bf(v - bf2f(h));
            }
        }
    }

    f32x4 acc_o[8];
    #pragma unroll
    for (int dt = 0; dt < 8; ++dt) acc_o[dt] = (f32x4){0.f, 0.f, 0.f, 0.f};
    float densum = 0.0f;

    for (int kci = 0; kci < 2; ++kci) {
        int kc = kci ? ((c + 511) & 511) : c;
        __syncthreads();                        // prev PV reads of kvs done
        if (tid < 64) tk_s[tid] = stb[kc * 64 + tid];
        __syncthreads();

        // ---- stage K_hat (hi/lo bf16 split), natural [64][136]
        #pragma unroll
        for (int u = 0; u < 8; ++u) {
            int fi = u * 256 + tid;
            int token = fi >> 5, cc = fi & 31;
            float4 vv = *(const float4*)(knorm +
                            (((size_t)b << 12) + tk_s[token]) * D_ + cc * 4);
            float xv[4] = {vv.x, vv.y, vv.z, vv.w};
            short4v h4, l4;
            #pragma unroll
            for (int j = 0; j < 4; ++j) {
                short h = f2bf(xv[j]);
                h4[j] = h;
                l4[j] = f2bf(xv[j] - bf2f(h));
            }
            *(short4v*)&kvs[token * 136 + cc * 4] = h4;
            *(short4v*)&kvs[8704 + token * 136 + cc * 4] = l4;
        }
        __syncthreads();

        // ---- dots^T = K_hat . Q^T  (row = k, col = q), 3-term split
        f32x4 e4[4];
        #pragma unroll
        for (int kt = 0; kt < 4; ++kt) {
            f32x4 acc = (f32x4){0.f, 0.f, 0.f, 0.f};
            #pragma unroll
            for (int s4 = 0; s4 < 4; ++s4) {
                bf16x8 ah = *(const bf16x8*)&kvs[(kt * 16 + m) * 136 + s4 * 32 + g * 8];
                bf16x8 al = *(const bf16x8*)&kvs[8704 + (kt * 16 + m) * 136 + s4 * 32 + g * 8];
                acc = __builtin_amdgcn_mfma_f32_16x16x32_bf16(ah, qh[s4], acc, 0, 0, 0);
                acc = __builtin_amdgcn_mfma_f32_16x16x32_bf16(ah, ql[s4], acc, 0, 0, 0);
                acc = __builtin_amdgcn_mfma_f32_16x16x32_bf16(al, qh[s4], acc, 0, 0, 0);
            }
            int4v kt4 = *(const int4v*)&tk_s[kt * 16 + g * 4];
            f32x4 e;
            #pragma unroll
            for (int r = 0; r < 4; ++r) {
                float ev = __expf(acc[r]);
                ev = (kt4[r] == qtok_m) ? 0.0f : ev;
                e[r] = ev;
                densum += ev;
            }
            e4[kt] = e;
        }
        __syncthreads();                        // K reads done before V overwrite

        // ---- stage V^T: in-register 4x4 transpose -> subtiled [kg][128][8]
        #pragma unroll
        for (int up = 0; up < 4; ++up) {
            int kq8 = w * 16 + (up & 1) * 8;    // 8-token group (wave-local)
            int cc = (up >> 1) * 16 + m;
            int d0 = cc * 4;
            float4 va = *(const float4*)(vglob +
                           (((size_t)b << 12) + tk_s[kq8 + g]) * D_ + d0);
            float4 vb = *(const float4*)(vglob +
                           (((size_t)b << 12) + tk_s[kq8 + 4 + g]) * D_ + d0);
            float wa[4], wb[4];
            transpose4(va, g, wa);              // wa[i] = (token kq8+i, dim d0+g)
            transpose4(vb, g, wb);
            int d = d0 + g;
            int kg = kq8 >> 3;
            bf16x8 hv, lv;
            #pragma unroll
            for (int i = 0; i < 4; ++i) {
                short h = f2bf(wa[i]);
                hv[i] = h; lv[i] = f2bf(wa[i] - bf2f(h));
                short h2 = f2bf(wb[i]);
                hv[4 + i] = h2; lv[4 + i] = f2bf(wb[i] - bf2f(h2));
            }
            *(bf16x8*)&kvs[(kg * 128 + d) * 8] = hv;
            *(bf16x8*)&kvs[8192 + (kg * 128 + d) * 8] = lv;
        }
        __syncthreads();

        // ---- PV: A = P (built via shuffles from e4), B = V^T subtiles
        #pragma unroll
        for (int s = 0; s < 2; ++s) {
            float pav[8];
            #pragma unroll
            for (int c2 = 0; c2 < 2; ++c2) {
                int srcLane = ((g & 1) * 2 + c2) * 16 + m;
                #pragma unroll
                for (int r = 0; r < 4; ++r) {
                    float v0 = __shfl(e4[2 * s][r], srcLane, 64);
                    float v1 = __shfl(e4[2 * s + 1][r], srcLane, 64);
                    pav[c2 * 4 + r] = (g >> 1) ? v1 : v0;
                }
            }
            bf16x8 pah, pal;
            #pragma unroll
            for (int j = 0; j < 8; ++j) {
                short h = f2bf(pav[j]);
                pah[j] = h;
                pal[j] = f2bf(pav[j] - bf2f(h));
            }
            #pragma unroll
            for (int dt = 0; dt < 8; ++dt) {
                int base = ((s * 4 + g) * 128 + dt * 16 + m) * 8;
                bf16x8 vh = *(const bf16x8*)&kvs[base];
                bf16x8 vl = *(const bf16x8*)&kvs[8192 + base];
                acc_o[dt] = __builtin_amdgcn_mfma_f32_16x16x32_bf16(pah, vh, acc_o[dt], 0, 0, 0);
                acc_o[dt] = __builtin_amdgcn_mfma_f32_16x16x32_bf16(pal, vh, acc_o[dt], 0, 0, 0);
                acc_o[dt] = __builtin_amdgcn_mfma_f32_16x16x32_bf16(pah, vl, acc_o[dt], 0, 0, 0);
            }
        }
    }

    // ---- epilogue: denominator + output atomics
    densum += __shfl_xor(densum, 16, 64);
    densum += __shfl_xor(densum, 32, 64);
    if (g == 0) atomicAdd(den + ((size_t)b << 12) + qtok_m, densum);

    int4v q4tok = *(const int4v*)&tq_s[w * 16 + g * 4];
    #pragma unroll
    for (int r = 0; r < 4; ++r) {
        float* obase = outnum + ((((size_t)b << 12) + q4tok[r]) * D_);
        #pragma unroll
        for (int dt = 0; dt < 8; ++dt)
            atomicAdd(obase + dt * 16 + m, acc_o[dt][r]);
    }
}

// ---------------------------------------------------------------- divide
__global__ __launch_bounds__(256) void div_kernel(float* __restrict__ out,
                                                  const float* __restrict__ den) {
    int i = blockIdx.x * 256 + threadIdx.x;  // float4 index
    float4 o = ((float4*)out)[i];
    float dn = den[i >> 5];
    ((float4*)out)[i] = make_float4(o.x / dn, o.y / dn, o.z / dn, o.w / dn);
}

// ---------------------------------------------------------------- launch
extern "C" void kernel_launch(void* const* d_in, const int* in_sizes, int n_in,
                              void* d_out, int out_size, void* d_ws, size_t ws_size,
                              hipStream_t stream) {
    const float* qk  = (const float*)d_in[0];
    const float* v   = (const float*)d_in[1];
    const float* rot = (const float*)d_in[2];
    float* out = (float*)d_out;

    char* ws = (char*)d_ws;
    float* knorm  = (float*)ws;                       // 33,554,432 B
    int* buckets  = (int*)(ws + 33554432);            //  2,097,152 B
    int* st       = (int*)(ws + 35651584);            //  2,097,152 B
    float* den    = (float*)(ws + 37748736);          //    262,144 B

    hipMemsetAsync(out, 0, (size_t)B_ * S_ * D_ * 4, stream);
    hipMemsetAsync(den, 0, (size_t)B_ * S_ * 4, stream);

    norm_kernel<<<B_ * S_ / 4, 256, 0, stream>>>(qk, knorm);
    hash_kernel<<<B_ * (S_ / 64), 256, 0, stream>>>(qk, rot, buckets);
    sort_kernel<<<B_ * H_, 256, 0, stream>>>(buckets, st);
    attn_mfma_kernel<<<B_ * C_, 256, 0, stream>>>(qk, knorm, v, st, out, den);
    div_kernel<<<B_ * S_ * D_ / 4 / 256, 256, 0, stream>>>(out, den);
}

// Round 3
// 497.513 us; speedup vs baseline: 3.1832x; 1.0243x over previous
//
#include <hip/hip_runtime.h>
#include <hip/hip_bf16.h>

// LSH attention (Reformer-style), B=16, S=4096, D=128, H=8, bucket=64.
// Pipeline: rnorm -> hash (f64 argmax) -> counting sort ->
// MFMA chunked attention (bf16 3-term split, swizzled LDS, atomics) -> divide.

#define B_ 16
#define S_ 4096
#define D_ 128
#define H_ 8
#define NB_ 64          // n_buckets
#define C_ 512          // H * NB = chunks per batch
#define W_ 64           // bucket/window size

typedef __attribute__((ext_vector_type(8))) short bf16x8;
typedef __attribute__((ext_vector_type(4))) short short4v;
typedef __attribute__((ext_vector_type(4))) float f32x4;
typedef __attribute__((ext_vector_type(4))) int int4v;

__device__ __forceinline__ short f2bf(float x) {
    __hip_bfloat16 b = __float2bfloat16(x);   // RNE
    return *reinterpret_cast<short*>(&b);
}
__device__ __forceinline__ float bf2f(short h) {
    unsigned int u = ((unsigned int)(unsigned short)h) << 16;
    float f;
    __builtin_memcpy(&f, &u, 4);
    return f;
}

// ---------------------------------------------------------------- row 1/norm
// rnrm[b*S+t] = 1 / max(||qk[b,t,:]||, 1e-12); one 32-lane group per row.
__global__ __launch_bounds__(256) void norm_kernel(const float* __restrict__ qk,
                                                   float* __restrict__ rnrm) {
    int half = threadIdx.x >> 5;            // 0..7 rows in this block
    int lane32 = threadIdx.x & 31;
    size_t row = (size_t)blockIdx.x * 8 + half;
    float4 vv = ((const float4*)(qk + row * D_))[lane32];
    float ss = vv.x * vv.x + vv.y * vv.y + vv.z * vv.z + vv.w * vv.w;
    #pragma unroll
    for (int m = 1; m < 32; m <<= 1) ss += __shfl_xor(ss, m, 64);
    if (lane32 == 0) rnrm[row] = 1.0f / fmaxf(sqrtf(ss), 1e-12f);
}

// ---------------------------------------------------------------- hashing
__global__ __launch_bounds__(256) void hash_kernel(const float* __restrict__ qk,
                                                   const float* __restrict__ rot,
                                                   int* __restrict__ buckets) {
    __shared__ float qtile[64 * 132];
    __shared__ float rtile[128 * 32];
    int b = blockIdx.x >> 6;
    int tile = blockIdx.x & 63;
    int tid = threadIdx.x;

    const float* qbase = qk + ((size_t)b * S_ + (size_t)tile * 64) * D_;
    #pragma unroll
    for (int u = 0; u < 8; ++u) {
        int fi = u * 256 + tid;
        int row = fi >> 5, c = fi & 31;
        float4 vv = ((const float4*)qbase)[fi];
        *((float4*)(qtile + row * 132 + c * 4)) = vv;
    }

    int tok = tid >> 2, part = tid & 3;
    int t = tile * 64 + tok;

    for (int h = 0; h < H_; ++h) {
        __syncthreads();
        #pragma unroll
        for (int u = 0; u < 4; ++u) {
            int fi = u * 256 + tid;
            int f = fi >> 3, i4 = fi & 7;
            ((float4*)rtile)[f * 8 + i4] = ((const float4*)rot)[f * 64 + h * 8 + i4];
        }
        __syncthreads();

        double pd[8] = {0, 0, 0, 0, 0, 0, 0, 0};
        #pragma unroll 2
        for (int f = 0; f < 128; ++f) {
            double q = (double)qtile[tok * 132 + f];
            float4 r0 = *((const float4*)(rtile + f * 32 + part * 8));
            float4 r1 = *((const float4*)(rtile + f * 32 + part * 8 + 4));
            pd[0] = fma(q, (double)r0.x, pd[0]);
            pd[1] = fma(q, (double)r0.y, pd[1]);
            pd[2] = fma(q, (double)r0.z, pd[2]);
            pd[3] = fma(q, (double)r0.w, pd[3]);
            pd[4] = fma(q, (double)r1.x, pd[4]);
            pd[5] = fma(q, (double)r1.y, pd[5]);
            pd[6] = fma(q, (double)r1.z, pd[6]);
            pd[7] = fma(q, (double)r1.w, pd[7]);
        }

        double bv = -1e300; int bi = 0;
        #pragma unroll
        for (int ii = 0; ii < 8; ++ii) {
            int i = part * 8 + ii;
            double v = pd[ii];
            if (v > bv || (v == bv && i < bi)) { bv = v; bi = i; }
            double nv = -v; int ni = i + 32;
            if (nv > bv || (nv == bv && ni < bi)) { bv = nv; bi = ni; }
        }
        #pragma unroll
        for (int m = 1; m <= 2; m <<= 1) {
            double ov = __shfl_xor(bv, m, 64);
            int oi = __shfl_xor(bi, m, 64);
            if (ov > bv || (ov == bv && oi < bi)) { bv = ov; bi = oi; }
        }
        if (part == 0) buckets[(((size_t)b * H_ + h) << 12) + t] = bi;
    }
}

// ---------------------------------------------------------------- stable counting sort
__global__ __launch_bounds__(256) void sort_kernel(const int* __restrict__ buckets,
                                                   int* __restrict__ st) {
    __shared__ unsigned short hist[256][64];
    __shared__ int base[64];
    __shared__ int totals[64];
    int tid = threadIdx.x;
    const int* bkrow = buckets + (size_t)blockIdx.x * S_;

    unsigned int* h32 = (unsigned int*)hist;
    #pragma unroll
    for (int u = 0; u < 32; ++u) h32[u * 256 + tid] = 0;
    __syncthreads();

    #pragma unroll
    for (int u = 0; u < 16; ++u) {
        int t = tid * 16 + u;
        int bk = bkrow[t];
        hist[tid][bk]++;
    }
    __syncthreads();

    if (tid < 64) {
        int bucket = tid;
        int run = 0;
        for (int ch = 0; ch < 256; ++ch) {
            int v = hist[ch][bucket];
            hist[ch][bucket] = (unsigned short)run;
            run += v;
        }
        totals[bucket] = run;
    }
    __syncthreads();
    if (tid == 0) {
        int acc = 0;
        for (int k = 0; k < 64; ++k) { base[k] = acc; acc += totals[k]; }
    }
    __syncthreads();

    int* strow = st + (size_t)blockIdx.x * S_;
    #pragma unroll
    for (int u = 0; u < 16; ++u) {
        int t = tid * 16 + u;
        int bk = bkrow[t];
        int off = hist[tid][bk];
        hist[tid][bk] = (unsigned short)(off + 1);
        strow[base[bk] + off] = t;
    }
}

// ---------------------------------------------------------------- in-reg 4x4 transpose
__device__ __forceinline__ void transpose4(const float4 v, int g, float (&w_)[4]) {
    bool b0 = (g & 1) != 0, b1 = (g & 2) != 0;
    float k0 = b1 ? v.z : v.x;
    float k1 = b1 ? v.w : v.y;
    float s0 = b1 ? v.x : v.z;
    float s1 = b1 ? v.y : v.w;
    float r0 = __shfl_xor(s0, 32, 64);
    float r1 = __shfl_xor(s1, 32, 64);
    float kq_ = b0 ? k1 : k0;
    float rq_ = b0 ? r1 : r0;
    float sk  = b0 ? k0 : k1;
    float sr  = b0 ? r0 : r1;
    float tk_ = __shfl_xor(sk, 16, 64);
    float tr_ = __shfl_xor(sr, 16, 64);
    float A0 = b0 ? tk_ : kq_;
    float A1 = b0 ? kq_ : tk_;
    float B0 = b0 ? tr_ : rq_;
    float B1 = b0 ? rq_ : tr_;
    w_[0] = b1 ? B0 : A0;
    w_[1] = b1 ? B1 : A1;
    w_[2] = b1 ? A0 : B0;
    w_[3] = b1 ? A1 : B1;
}

// ---------------------------------------------------------------- MFMA attention
// One block per (b, chunk c): 64 q vs 128 k (chunks c, c-1 mod 512).
// K_hat LDS: [64 rows][256 B], 16B-slot ^= (row&7)  -> conflict-free b128.
// V^T  LDS: [kg][swz(d)][8 tok], swz(d)=d^((d>>2)&6) -> conflict-free b128 r+w.
__global__ __launch_bounds__(256) void attn_mfma_kernel(
        const float* __restrict__ qk, const float* __restrict__ rnrm,
        const float* __restrict__ vglob, const int* __restrict__ st,
        float* __restrict__ outnum, float* __restrict__ den) {
    __shared__ int tq_s[64];
    __shared__ int tk_s[64];
    // union: {khi shorts [0,8192), klo [8192,16384)} | {vhi, vlo}
    __shared__ short kvs[16384];

    const int bc = blockIdx.x;
    const int b  = bc >> 9;
    const int c  = bc & 511;
    const int tid = threadIdx.x;
    const int w   = tid >> 6;   // wave 0..3
    const int l   = tid & 63;
    const int g   = l >> 4;     // quad 0..3
    const int m   = l & 15;

    const int* stb = st + ((size_t)b << 15);
    if (tid < 64) tq_s[tid] = stb[c * 64 + tid];
    __syncthreads();

    const int qtok_m = tq_s[w * 16 + m];   // this lane's q column token

    // ---- Q B-fragments (col=m, k-elems d = s4*32 + g*8 + j), scale folded
    bf16x8 qh[4], ql[4];
    {
        const float scale = 0.08838834764831845f;   // D^-0.5
        const float* qrow = qk + (((size_t)b << 12) + qtok_m) * D_;
        #pragma unroll
        for (int s4 = 0; s4 < 4; ++s4) {
            float4 xa = *(const float4*)(qrow + s4 * 32 + g * 8);
            float4 xb = *(const float4*)(qrow + s4 * 32 + g * 8 + 4);
            float xv[8] = {xa.x, xa.y, xa.z, xa.w, xb.x, xb.y, xb.z, xb.w};
            #pragma unroll
            for (int j = 0; j < 8; ++j) {
                float v = xv[j] * scale;
                short h = f2bf(v);
                qh[s4][j] = h;
                ql[s4][j] = f2bf(v - bf2f(h));
            }
        }
    }

    f32x4 acc_o[8];
    #pragma unroll
    for (int dt = 0; dt < 8; ++dt) acc_o[dt] = (f32x4){0.f, 0.f, 0.f, 0.f};
    float densum = 0.0f;

    for (int kci = 0; kci < 2; ++kci) {
        int kc = kci ? ((c + 511) & 511) : c;
        __syncthreads();                        // prev PV reads of kvs done
        if (tid < 64) tk_s[tid] = stb[kc * 64 + tid];
        __syncthreads();

        // ---- stage K_hat = qk[token]*rnrm (hi/lo bf16), swizzled rows
        #pragma unroll
        for (int u = 0; u < 8; ++u) {
            int fi = u * 256 + tid;
            int token = fi >> 5, cc = fi & 31;
            int tkt = tk_s[token];
            float rn = rnrm[((size_t)b << 12) + tkt];
            float4 vv = *(const float4*)(qk + (((size_t)b << 12) + tkt) * D_ + cc * 4);
            float xv[4] = {vv.x * rn, vv.y * rn, vv.z * rn, vv.w * rn};
            short4v h4, l4;
            #pragma unroll
            for (int j = 0; j < 4; ++j) {
                short h = f2bf(xv[j]);
                h4[j] = h;
                l4[j] = f2bf(xv[j] - bf2f(h));
            }
            int kw = token * 128 + ((((cc >> 1) ^ (token & 7)) << 3) | ((cc & 1) << 2));
            *(short4v*)&kvs[kw] = h4;
            *(short4v*)&kvs[8192 + kw] = l4;
        }
        __syncthreads();

        // ---- dots^T = K_hat . Q^T  (row = k, col = q), 3-term split
        f32x4 e4[4];
        #pragma unroll
        for (int kt = 0; kt < 4; ++kt) {
            f32x4 acc = (f32x4){0.f, 0.f, 0.f, 0.f};
            #pragma unroll
            for (int s4 = 0; s4 < 4; ++s4) {
                int kr = (kt * 16 + m) * 128 + (((s4 * 4 + g) ^ (m & 7)) << 3);
                bf16x8 ah = *(const bf16x8*)&kvs[kr];
                bf16x8 al = *(const bf16x8*)&kvs[8192 + kr];
                acc = __builtin_amdgcn_mfma_f32_16x16x32_bf16(ah, qh[s4], acc, 0, 0, 0);
                acc = __builtin_amdgcn_mfma_f32_16x16x32_bf16(ah, ql[s4], acc, 0, 0, 0);
                acc = __builtin_amdgcn_mfma_f32_16x16x32_bf16(al, qh[s4], acc, 0, 0, 0);
            }
            int4v kt4 = *(const int4v*)&tk_s[kt * 16 + g * 4];
            f32x4 e;
            #pragma unroll
            for (int r = 0; r < 4; ++r) {
                float ev = __expf(acc[r]);
                ev = (kt4[r] == qtok_m) ? 0.0f : ev;
                e[r] = ev;
                densum += ev;
            }
            e4[kt] = e;
        }
        __syncthreads();                        // K reads done before V overwrite

        // ---- stage V^T: in-register 4x4 transpose -> swizzled [kg][swz(d)][8]
        #pragma unroll
        for (int up = 0; up < 4; ++up) {
            int kq8 = w * 16 + (up & 1) * 8;    // 8-token group (wave-local)
            int cc = (up >> 1) * 16 + m;
            int d0 = cc * 4;
            float4 va = *(const float4*)(vglob +
                           (((size_t)b << 12) + tk_s[kq8 + g]) * D_ + d0);
            float4 vb = *(const float4*)(vglob +
                           (((size_t)b << 12) + tk_s[kq8 + 4 + g]) * D_ + d0);
            float wa[4], wb[4];
            transpose4(va, g, wa);              // wa[i] = (token kq8+i, dim d0+g)
            transpose4(vb, g, wb);
            int d = d0 + g;
            int ds = d ^ ((d >> 2) & 6);
            int kg = kq8 >> 3;
            bf16x8 hv, lv;
            #pragma unroll
            for (int i = 0; i < 4; ++i) {
                short h = f2bf(wa[i]);
                hv[i] = h; lv[i] = f2bf(wa[i] - bf2f(h));
                short h2 = f2bf(wb[i]);
                hv[4 + i] = h2; lv[4 + i] = f2bf(wb[i] - bf2f(h2));
            }
            int idx = (kg * 128 + ds) * 8;
            *(bf16x8*)&kvs[idx] = hv;
            *(bf16x8*)&kvs[8192 + idx] = lv;
        }
        __syncthreads();

        // ---- PV: A = P (built via shuffles from e4), B = V^T subtiles
        #pragma unroll
        for (int s = 0; s < 2; ++s) {
            float pav[8];
            #pragma unroll
            for (int c2 = 0; c2 < 2; ++c2) {
                int srcLane = ((g & 1) * 2 + c2) * 16 + m;
                #pragma unroll
                for (int r = 0; r < 4; ++r) {
                    float v0 = __shfl(e4[2 * s][r], srcLane, 64);
                    float v1 = __shfl(e4[2 * s + 1][r], srcLane, 64);
                    pav[c2 * 4 + r] = (g >> 1) ? v1 : v0;
                }
            }
            bf16x8 pah, pal;
            #pragma unroll
            for (int j = 0; j < 8; ++j) {
                short h = f2bf(pav[j]);
                pah[j] = h;
                pal[j] = f2bf(pav[j] - bf2f(h));
            }
            #pragma unroll
            for (int dt = 0; dt < 8; ++dt) {
                int d = dt * 16 + m;
                int ds = d ^ ((d >> 2) & 6);
                int base = ((s * 4 + g) * 128 + ds) * 8;
                bf16x8 vh = *(const bf16x8*)&kvs[base];
                bf16x8 vl = *(const bf16x8*)&kvs[8192 + base];
                acc_o[dt] = __builtin_amdgcn_mfma_f32_16x16x32_bf16(pah, vh, acc_o[dt], 0, 0, 0);
                acc_o[dt] = __builtin_amdgcn_mfma_f32_16x16x32_bf16(pal, vh, acc_o[dt], 0, 0, 0);
                acc_o[dt] = __builtin_amdgcn_mfma_f32_16x16x32_bf16(pah, vl, acc_o[dt], 0, 0, 0);
            }
        }
    }

    // ---- epilogue: denominator + output atomics
    densum += __shfl_xor(densum, 16, 64);
    densum += __shfl_xor(densum, 32, 64);
    if (g == 0) atomicAdd(den + ((size_t)b << 12) + qtok_m, densum);

    int4v q4tok = *(const int4v*)&tq_s[w * 16 + g * 4];
    #pragma unroll
    for (int r = 0; r < 4; ++r) {
        float* obase = outnum + ((((size_t)b << 12) + q4tok[r]) * D_);
        #pragma unroll
        for (int dt = 0; dt < 8; ++dt)
            atomicAdd(obase + dt * 16 + m, acc_o[dt][r]);
    }
}

// ---------------------------------------------------------------- divide
__global__ __launch_bounds__(256) void div_kernel(float* __restrict__ out,
                                                  const float* __restrict__ den) {
    int i = blockIdx.x * 256 + threadIdx.x;  // float4 index
    float4 o = ((float4*)out)[i];
    float dn = den[i >> 5];
    ((float4*)out)[i] = make_float4(o.x / dn, o.y / dn, o.z / dn, o.w / dn);
}

// ---------------------------------------------------------------- launch
extern "C" void kernel_launch(void* const* d_in, const int* in_sizes, int n_in,
                              void* d_out, int out_size, void* d_ws, size_t ws_size,
                              hipStream_t stream) {
    const float* qk  = (const float*)d_in[0];
    const float* v   = (const float*)d_in[1];
    const float* rot = (const float*)d_in[2];
    float* out = (float*)d_out;

    char* ws = (char*)d_ws;
    float* rnrm   = (float*)ws;                       //   262,144 B
    int* buckets  = (int*)(ws + 262144);              // 2,097,152 B
    int* st       = (int*)(ws + 2359296);             // 2,097,152 B
    float* den    = (float*)(ws + 4456448);           //   262,144 B

    hipMemsetAsync(out, 0, (size_t)B_ * S_ * D_ * 4, stream);
    hipMemsetAsync(den, 0, (size_t)B_ * S_ * 4, stream);

    norm_kernel<<<B_ * S_ / 8, 256, 0, stream>>>(qk, rnrm);
    hash_kernel<<<B_ * (S_ / 64), 256, 0, stream>>>(qk, rot, buckets);
    sort_kernel<<<B_ * H_, 256, 0, stream>>>(buckets, st);
    attn_mfma_kernel<<<B_ * C_, 256, 0, stream>>>(qk, rnrm, v, st, out, den);
    div_kernel<<<B_ * S_ * D_ / 4 / 256, 256, 0, stream>>>(out, den);
}